// Round 12
// baseline (430.556 us; speedup 1.0000x reference)
//
#include <hip/hip_runtime.h>

typedef _Float16 v8h __attribute__((ext_vector_type(8)));
typedef float f32x4 __attribute__((ext_vector_type(4)));

#define BB 128
#define TT 512
#define NN 200
#define START_IDX 1
#define END_IDX 2

#define NT 256   // 4 waves
#define NCOL 16  // batch columns per block
#define SP 232   // p stride in halves: 464B = 16B-aligned, bank-balanced b128 reads
#define NBLK (BB / NCOL) // 8

__device__ __forceinline__ void sync_lds() {
  asm volatile("s_waitcnt lgkmcnt(0)" ::: "memory");
  __builtin_amdgcn_s_barrier();
}

__device__ __forceinline__ v8h zero8() {
  v8h r;
#pragma unroll
  for (int e = 0; e < 8; ++e) r[e] = (_Float16)0.f;
  return r;
}

__global__ __attribute__((amdgpu_flat_work_group_size(NT, NT),
                          amdgpu_waves_per_eu(1, 1)))
void crf_fwd_kernel(const float* __restrict__ unary, const int* __restrict__ tags,
                    const int* __restrict__ lengths, const float* __restrict__ trans,
                    float* __restrict__ ws) {
  const int blk = blockIdx.x; // 0..7
  const int b0 = blk * NCOL;
  const int tid = threadIdx.x;
  const int lane = tid & 63;
  const int wave = tid >> 6; // 0..3
  const int m15 = lane & 15; // A-row-in-tile / B,D-column (batch), per MFMA layouts
  const int g = lane >> 4;   // 0..3: k-group (A,B) / row-group (D)
  const bool w3 = (wave == 3);

  // p: fp16, col-major [16 cols][SP rows]. k 200..231 stay zero. Single-buffered:
  // step = {read all -> bar1 -> write} so frozen columns just skip writes.
  __shared__ __align__(16) _Float16 pL[NCOL * SP];
  __shared__ __align__(16) float padsL[NCOL * 4]; // per-(col,wave) partial max of p
  __shared__ __align__(16) float gred[NCOL * 4];
  __shared__ float goldL[NCOL];
  __shared__ float a2L[NCOL];
  __shared__ __align__(16) float big[20480]; // 80KB pin: 1 block/CU + VGPR budget

  // ---- init p: every col = e_START; pads: wave0 (tile 0 holds row START) = 1
  for (int i = tid; i < NCOL * SP; i += NT) {
    const int r = i - (i / SP) * SP;
    pL[i] = (r == START_IDX) ? (_Float16)1.0f : (_Float16)0.0f;
  }
  if (tid < 64) padsL[tid] = ((tid & 3) == 0) ? 1.0f : 0.0f;

  const int lenc = lengths[b0 + m15]; // my column's length
  int maxlen = lenc;
#pragma unroll
  for (int k = 1; k < 16; k <<= 1) maxlen = max(maxlen, __shfl_xor(maxlen, k, 64));
  if (maxlen < 0) big[20479] = 0.f; // never true; keeps pin alive

  // ---- A-fragments: E = exp(trans), row = tilebase + m15, k = 32kc + 8g + e.
  // Same (g,e)->k map is used for the B reads, so any true HW k-permutation
  // cancels (dot products are permutation-invariant when A,B share the map).
  const int rb0 = 16 * wave, rb1 = rb0 + 64, rb2 = rb0 + 128; // tiles w, w+4, w+8
  v8h Af0[7], Af1[7], Af2[7], Af3[7];
  auto mkfrag = [&](int row, int kc) -> v8h {
    const int k8 = 32 * kc + 8 * g;
    if (row < NN && k8 < NN) { // k8 either fully valid (k8+7<=199) or fully not
      const float4 a = *reinterpret_cast<const float4*>(trans + row * NN + k8);
      const float4 b = *reinterpret_cast<const float4*>(trans + row * NN + k8 + 4);
      v8h r;
      r[0] = (_Float16)__expf(a.x); r[1] = (_Float16)__expf(a.y);
      r[2] = (_Float16)__expf(a.z); r[3] = (_Float16)__expf(a.w);
      r[4] = (_Float16)__expf(b.x); r[5] = (_Float16)__expf(b.y);
      r[6] = (_Float16)__expf(b.z); r[7] = (_Float16)__expf(b.w);
      return r;
    }
    return zero8();
  };
#pragma unroll
  for (int kc = 0; kc < 7; ++kc) {
    Af0[kc] = mkfrag(rb0 + m15, kc);
    Af1[kc] = mkfrag(rb1 + m15, kc);
    Af2[kc] = mkfrag(rb2 + m15, kc);
    Af3[kc] = w3 ? mkfrag(192 + m15, kc) : zero8(); // tile 12: rows 192..207
  }

  // ---- gold path scores, one col per lane-mod-16, 16 t-slices
  {
    const int bG = b0 + m15;
    const int lenG = lenc;
    const int sG = tid >> 4; // wave*4 + g
    float gacc = 0.f;
    for (int t = sG; t < lenG; t += 16) {
      const int cur = tags[bG * TT + t];
      const int prev = (t == 0) ? START_IDX : tags[bG * TT + t - 1];
      gacc += trans[cur * NN + prev] + unary[(size_t)bG * (TT * NN) + t * NN + cur];
    }
    gacc += __shfl_xor(gacc, 16, 64);
    gacc += __shfl_xor(gacc, 32, 64);
    if (g == 0) gred[m15 * 4 + wave] = gacc;
    __syncthreads();
    if (tid < 16) {
      const float4 gp = *reinterpret_cast<const float4*>(&gred[tid * 4]);
      const int lt = tags[(b0 + tid) * TT + lengths[b0 + tid] - 1];
      goldL[tid] = gp.x + gp.y + gp.z + gp.w + trans[END_IDX * NN + lt];
    }
  }

  // ---- u prefetch (2-step rename): col = m15, rows = tilebase + 4g .. +3
  const float* uCol = unary + (size_t)(b0 + m15) * (TT * NN);
  auto uload = [&](int t, int rb) -> float4 {
    return *reinterpret_cast<const float4*>(uCol + t * NN + rb + 4 * g);
  };
  const float4 fz = {0.f, 0.f, 0.f, 0.f};
  float4 e0A = uload(0, rb0), e1A = uload(0, rb1), e2A = uload(0, rb2);
  float4 e3A = (w3 && g < 2) ? uload(0, 192) : fz; // rows>=200: keep 0 (NaN guard)
  float4 e0B = uload(1, rb0), e1B = uload(1, rb1), e2B = uload(1, rb2);
  float4 e3B = (w3 && g < 2) ? uload(1, 192) : fz;

  float sc2 = 0.f; // per-col running scale, log2 domain: alpha = sc2*ln2 + log p
  __syncthreads();

  auto STEP = [&](int t, float4& e0, float4& e1, float4& e2, float4& e3) {
    // ---- R: read shared state (pads + B-fragments), then MFMA
    const float4 pv = *reinterpret_cast<const float4*>(&padsL[m15 * 4]);
    uint4 Bq[7];
#pragma unroll
    for (int kc = 0; kc < 7; ++kc)
      Bq[kc] = *reinterpret_cast<const uint4*>(
          reinterpret_cast<const char*>(pL) + 2 * (m15 * SP + 32 * kc + 8 * g));

    const float M = fmaxf(fmaxf(pv.x, pv.y), fmaxf(pv.z, pv.w)); // max p_t[col]
    const float rcpM = __builtin_amdgcn_rcpf(M);
    const bool pr = (t < lenc);
    sc2 += pr ? __log2f(M) : 0.f;

    f32x4 ac0 = {0.f, 0.f, 0.f, 0.f};
    f32x4 ac1 = {0.f, 0.f, 0.f, 0.f};
    f32x4 ac2 = {0.f, 0.f, 0.f, 0.f};
    f32x4 ac3 = {0.f, 0.f, 0.f, 0.f};
#pragma unroll
    for (int kc = 0; kc < 7; ++kc) {
      const v8h Bk = __builtin_bit_cast(v8h, Bq[kc]);
      ac0 = __builtin_amdgcn_mfma_f32_16x16x32_f16(Af0[kc], Bk, ac0, 0, 0, 0);
      ac1 = __builtin_amdgcn_mfma_f32_16x16x32_f16(Af1[kc], Bk, ac1, 0, 0, 0);
      ac2 = __builtin_amdgcn_mfma_f32_16x16x32_f16(Af2[kc], Bk, ac2, 0, 0, 0);
      if (w3)
        ac3 = __builtin_amdgcn_mfma_f32_16x16x32_f16(Af3[kc], Bk, ac3, 0, 0, 0);
    }
    // scale factors exp(u)/M (consumed-set u; overlaps MFMA on the trans pipe)
    float ex0[4], ex1[4], ex2[4], ex3[4];
    ex0[0] = __expf(e0.x) * rcpM; ex0[1] = __expf(e0.y) * rcpM;
    ex0[2] = __expf(e0.z) * rcpM; ex0[3] = __expf(e0.w) * rcpM;
    ex1[0] = __expf(e1.x) * rcpM; ex1[1] = __expf(e1.y) * rcpM;
    ex1[2] = __expf(e1.z) * rcpM; ex1[3] = __expf(e1.w) * rcpM;
    ex2[0] = __expf(e2.x) * rcpM; ex2[1] = __expf(e2.y) * rcpM;
    ex2[2] = __expf(e2.z) * rcpM; ex2[3] = __expf(e2.w) * rcpM;
    ex3[0] = __expf(e3.x) * rcpM; ex3[1] = __expf(e3.y) * rcpM;
    ex3[2] = __expf(e3.z) * rcpM; ex3[3] = __expf(e3.w) * rcpM;

    sync_lds(); // bar1: all reads of p/pads complete before anyone writes

    // ---- E: epilogue. D layout: row = tilebase + 4g + reg, col = m15.
    float mx = 0.f;
    auto epi = [&](const f32x4& ac, const float* ex, int rb) {
      const float p0 = ac[0] * ex[0], p1 = ac[1] * ex[1];
      const float p2 = ac[2] * ex[2], p3 = ac[3] * ex[3];
      mx = fmaxf(mx, fmaxf(fmaxf(p0, p1), fmaxf(p2, p3)));
      uint2 wv;
      wv.x = __builtin_bit_cast(unsigned, __builtin_amdgcn_cvt_pkrtz(p0, p1));
      wv.y = __builtin_bit_cast(unsigned, __builtin_amdgcn_cvt_pkrtz(p2, p3));
      if (pr)
        *reinterpret_cast<uint2*>(reinterpret_cast<char*>(pL) +
                                  2 * (m15 * SP + rb + 4 * g)) = wv;
    };
    epi(ac0, ex0, rb0);
    epi(ac1, ex1, rb1);
    epi(ac2, ex2, rb2);
    if (w3) epi(ac3, ex3, 192); // rows 200..207 write exact 0 (ac=0, ex finite)

    mx = fmaxf(mx, __shfl_xor(mx, 16, 64));
    mx = fmaxf(mx, __shfl_xor(mx, 32, 64));
    if (g == 0 && pr) padsL[m15 * 4 + wave] = mx;

    // ---- issue u prefetch for t+2 into the just-consumed set
    const int t2 = (t + 2 < TT) ? t + 2 : TT - 1;
    e0 = uload(t2, rb0); e1 = uload(t2, rb1); e2 = uload(t2, rb2);
    if (w3 && g < 2) e3 = uload(t2, 192);

    sync_lds(); // bar2: writes visible for next step's reads (vmcnt NOT drained)
  };

  int t = 0;
  for (; t + 1 < maxlen; t += 2) {
    STEP(t, e0A, e1A, e2A, e3A);
    STEP(t + 1, e0B, e1B, e2B, e3B);
  }
  if (t < maxlen) STEP(t, e0A, e1A, e2A, e3A);

  // ---- terminal: fwd[col] = sc2*ln2 + log(sum_j p[j,col] * exp(trans[END,j]))
  if (wave == 0 && g == 0) a2L[m15] = sc2;
  __syncthreads();
  const int colT = wave * 4 + g; // 16 cols over 4 waves x 4 groups
  float sum = 0.f;
#pragma unroll
  for (int k = 0; k < 13; ++k) {
    const int j = m15 + 16 * k;
    if (j < NN) {
      const float pj = (float)pL[colT * SP + j];
      sum += pj * __expf(trans[END_IDX * NN + j]);
    }
  }
#pragma unroll
  for (int k = 1; k < 16; k <<= 1) sum += __shfl_xor(sum, k, 64);
  if (m15 == 0) {
    const float fwd = a2L[colT] * 0.6931471805599453f + __logf(sum);
    ws[b0 + colT] = fwd - goldL[colT];
  }
}

__global__ void crf_reduce_kernel(const float* __restrict__ wsIn,
                                  float* __restrict__ out) {
  const int tid = threadIdx.x; // 128 threads
  float v = wsIn[tid];
#pragma unroll
  for (int k = 32; k >= 1; k >>= 1) v += __shfl_xor(v, k, 64);
  __shared__ float s2[2];
  if ((tid & 63) == 0) s2[tid >> 6] = v;
  __syncthreads();
  if (tid == 0) out[0] = (s2[0] + s2[1]) * (1.0f / 128.0f);
}

extern "C" void kernel_launch(void* const* d_in, const int* in_sizes, int n_in,
                              void* d_out, int out_size, void* d_ws, size_t ws_size,
                              hipStream_t stream) {
  const float* unary = (const float*)d_in[0];
  const int* tags = (const int*)d_in[1];
  const int* lengths = (const int*)d_in[2];
  const float* trans = (const float*)d_in[3];
  float* ws = (float*)d_ws;
  float* out = (float*)d_out;

  crf_fwd_kernel<<<NBLK, NT, 0, stream>>>(unary, tags, lengths, trans, ws);
  crf_reduce_kernel<<<1, 128, 0, stream>>>(ws, out);
}